// Round 7
// baseline (204.094 us; speedup 1.0000x reference)
//
#include <hip/hip_runtime.h>
#include <hip/hip_bf16.h>

// out[n] = b + e_x[n] * sum_m exp(2*GAMMA*dot(x_n,y_m)) * c[m]
// n=16384, m=8192, d=512.
// Round 7: r6 A-resident conflict-free structure + REGISTER DOUBLE-BUFFER:
// MFMA(chunk c) consumes fragments ds_read during iter c-1; iter c issues
// reads(c+1) + stage(c+2). MFMA never waits on same-iter LDS -> LDS queue
// (768 cyc/iter) overlaps MFMA (621 cyc/iter). One barrier/iter, waits are
// vmcnt(0)+lgkmcnt(0) on ops issued a full iteration earlier (~free).
//
// Workspace: Xb bf16[16384*512] @0, Yb bf16[8192*512] @16777216,
//            ex f32[16384] @25165824, cw f32[8192] @25231360.

#define GAMMA 0.002f

typedef __bf16 bf16x8 __attribute__((ext_vector_type(8)));
typedef float  f32x4  __attribute__((ext_vector_type(4)));
typedef __attribute__((address_space(3))) void lds_void_t;
typedef __attribute__((address_space(1))) const void gl_void_t;

// ---------------- prep: f32 -> bf16 + exp(-gamma*||row||^2) (xW==nullptr)
// or c[m] = exp(-gamma*||row||^2)*W[m]
__global__ __launch_bounds__(256) void prep_kernel(const float* __restrict__ src,
                                                   __bf16* __restrict__ dst,
                                                   float* __restrict__ fac,
                                                   const float* __restrict__ xW,
                                                   int nrows) {
    const int wid  = threadIdx.x >> 6;
    const int lane = threadIdx.x & 63;
    const int row  = blockIdx.x * 4 + wid;
    if (row >= nrows) return;
    const float4* s = reinterpret_cast<const float4*>(src + (size_t)row * 512);
    float4 v0 = s[lane * 2];
    float4 v1 = s[lane * 2 + 1];
    float acc = v0.x * v0.x + v0.y * v0.y + v0.z * v0.z + v0.w * v0.w
              + v1.x * v1.x + v1.y * v1.y + v1.z * v1.z + v1.w * v1.w;
    bf16x8 o;
    o[0] = (__bf16)v0.x; o[1] = (__bf16)v0.y; o[2] = (__bf16)v0.z; o[3] = (__bf16)v0.w;
    o[4] = (__bf16)v1.x; o[5] = (__bf16)v1.y; o[6] = (__bf16)v1.z; o[7] = (__bf16)v1.w;
    *reinterpret_cast<bf16x8*>(dst + (size_t)row * 512 + lane * 8) = o;
#pragma unroll
    for (int off = 32; off >= 1; off >>= 1) acc += __shfl_xor(acc, off, 64);
    if (lane == 0) {
        float e = __expf(-GAMMA * acc);
        fac[row] = xW ? e * xW[row] : e;
    }
}

__global__ void init_out(float* __restrict__ out, const float* __restrict__ b, int n) {
    int i = blockIdx.x * blockDim.x + threadIdx.x;
    if (i < n) out[i] = b[0];
}

// ---------------- LDS geometry (identical to r6, validated conflict-free) ----
// lA @0: 16 kchunks x 8 rowblocks x 1KB, k-major granules (g = kslot*16+row').
// lB @131072: 2 dbuf x 16 colblocks x 1KB, same micro-layout.
// Fragment read = block_base + lane*16 (linear, conflict-free).

#define READF(AF, BF, Q, RB) do { \
    const int aO_ = (Q) * 8192 + aRdBase; \
    const int bO_ = 131072 + (RB) * 16384 + bRdBase; \
    _Pragma("unroll") \
    for (int rb = 0; rb < 4; ++rb) \
        AF[rb] = *reinterpret_cast<const bf16x8*>(&smem[aO_ + rb * 1024]); \
    _Pragma("unroll") \
    for (int cb = 0; cb < 4; ++cb) \
        BF[cb] = *reinterpret_cast<const bf16x8*>(&smem[bO_ + cb * 1024]); \
} while (0)

#define STAGEB(S, BUF) do { \
    const __bf16* src_ = sBlane + (size_t)((S) >> 4) * 131072 + ((S) & 15) * 32; \
    _Pragma("unroll") \
    for (int jj = 0; jj < 2; ++jj) \
        __builtin_amdgcn_global_load_lds( \
            (gl_void_t*)(src_ + (2 * wid + jj) * 8192), \
            (lds_void_t*)(smem + 131072 + (BUF) * 16384 + (2 * wid + jj) * 1024), \
            16, 0, 0); \
} while (0)

#define MFMA16(AF, BF) do { \
    __builtin_amdgcn_s_setprio(1); \
    _Pragma("unroll") \
    for (int rb = 0; rb < 4; ++rb) \
        _Pragma("unroll") \
        for (int cb = 0; cb < 4; ++cb) \
            acc[rb][cb] = __builtin_amdgcn_mfma_f32_16x16x32_bf16( \
                AF[rb], BF[cb], acc[rb][cb], 0, 0, 0); \
    __builtin_amdgcn_s_setprio(0); \
} while (0)

#define EPI(P) do { \
    float cv_[4]; \
    _Pragma("unroll") \
    for (int cb = 0; cb < 4; ++cb) \
        cv_[cb] = cw[colBase + (P) * 256 + (wc * 4 + cb) * 16 + lcol]; \
    _Pragma("unroll") \
    for (int rb = 0; rb < 4; ++rb) \
        _Pragma("unroll") \
        for (int i2 = 0; i2 < 4; ++i2) { \
            float s_ = rowsum[rb][i2]; \
            _Pragma("unroll") \
            for (int cb = 0; cb < 4; ++cb) \
                s_ += __expf(0.004f * acc[rb][cb][i2]) * cv_[cb]; \
            rowsum[rb][i2] = s_; \
        } \
    _Pragma("unroll") \
    for (int rb = 0; rb < 4; ++rb) \
        _Pragma("unroll") \
        for (int cb = 0; cb < 4; ++cb) \
            acc[rb][cb] = (f32x4){0.f, 0.f, 0.f, 0.f}; \
} while (0)

#define SYNC asm volatile("s_waitcnt vmcnt(0) lgkmcnt(0)"); __builtin_amdgcn_s_barrier()

// grid: 256 blocks (1/CU), 512 threads (8 waves: 2 row-halves x 4 col-quarters).
__global__ __launch_bounds__(512, 2) void rbf_gemm(
    const __bf16* __restrict__ Xb, const __bf16* __restrict__ Yb,
    const float* __restrict__ ex, const float* __restrict__ cw,
    float* __restrict__ out) {
    __shared__ __align__(128) char smem[163840];

    const int tid  = threadIdx.x;
    const int wid  = tid >> 6;
    const int lane = tid & 63;
    const int wr   = wid >> 2;      // 0..1: row half (64 rows)
    const int wc   = wid & 3;       // 0..3: col quarter (64 cols of the 256-chunk)

    // XCD-aware block map (r5/r6-validated: FETCH = compulsory-only).
    const int pid = blockIdx.x;
    const int xcd = pid & 7;
    const int j   = pid >> 3;                  // 0..31
    const int ch  = xcd & 1;                   // col half of Y
    const int rg  = (xcd >> 1) * 32 + j;       // 0..127 row group
    const int rowBase = rg * 128;
    const int colBase = ch * 4096;

    const int l15 = lane & 15, l4 = lane >> 4;
    const int lane16 = lane * 16;
    const int aRdBase = wr * 4096 + lane16;
    const int bRdBase = wc * 4096 + lane16;

    // per-lane gather sources implementing the k-major LDS layout (linear dest)
    const __bf16* sAlane = Xb + (size_t)(rowBase + wid * 16 + l15) * 512 + l4 * 8;
    const __bf16* sBlane = Yb + (size_t)(colBase + l15) * 512 + l4 * 8;

    // ---- prologue: whole A panel + B chunks 0,1 into dbuf 0,1
#pragma unroll
    for (int q = 0; q < 16; ++q)
        __builtin_amdgcn_global_load_lds((gl_void_t*)(sAlane + q * 32),
            (lds_void_t*)(smem + q * 8192 + wid * 1024), 16, 0, 0);
    STAGEB(0, 0);
    STAGEB(1, 1);
    SYNC;

    f32x4 acc[4][4] = {};
    float rowsum[4][4] = {};
    const int lcol = l15, lrow = l4;

    bf16x8 af0[4], bf0[4], af1[4], bf1[4];
    READF(af0, bf0, 0, 0);               // fragments for chunk 0

    // ---- main: 256 chunks (16 col-panels x 16 kchunks), reg-double-buffered.
    for (int cc = 0; cc < 128; ++cc) {
        const int ce = 2 * cc;           // even chunk
        const int co = 2 * cc + 1;       // odd chunk
        // ---- even body: mfma(ce) from F0; read ce+1 -> F1; stage ce+2 -> buf0
        SYNC;
        READF(af1, bf1, ((ce + 1) & 15), 1);
        if (ce < 254) STAGEB(ce + 2, 0);
        MFMA16(af0, bf0);
        // ---- odd body: mfma(co) from F1; read co+1 -> F0; stage co+2 -> buf1
        SYNC;
        if (co < 255) READF(af0, bf0, ((co + 1) & 15), 0);
        if (co < 254) STAGEB(co + 2, 1);
        MFMA16(af1, bf1);
        if ((cc & 7) == 7) EPI(co >> 4); // full-K acc -> exp -> rowsum
    }

    // ---- final: 16-lane reduce + one atomic per (col-wave, n); out pre-init'd to b
#pragma unroll
    for (int rb = 0; rb < 4; ++rb)
#pragma unroll
        for (int i2 = 0; i2 < 4; ++i2) {
            float s = rowsum[rb][i2];
#pragma unroll
            for (int off = 1; off < 16; off <<= 1) s += __shfl_xor(s, off, 64);
            if (lcol == 0) {
                const int n = rowBase + wr * 64 + rb * 16 + lrow * 4 + i2;
                atomicAdd(&out[n], ex[n] * s);
            }
        }
}

extern "C" void kernel_launch(void* const* d_in, const int* in_sizes, int n_in,
                              void* d_out, int out_size, void* d_ws, size_t ws_size,
                              hipStream_t stream) {
    const float* X = (const float*)d_in[0];   // 16384 x 512
    const float* Y = (const float*)d_in[1];   //  8192 x 512
    const float* W = (const float*)d_in[2];   // 8192
    const float* b = (const float*)d_in[3];   // 1
    float* out = (float*)d_out;               // 16384

    char* ws = (char*)d_ws;
    __bf16* Xb = (__bf16*)(ws);
    __bf16* Yb = (__bf16*)(ws + 16777216);
    float*  ex = (float*)(ws + 16777216 + 8388608);
    float*  cw = (float*)(ws + 16777216 + 8388608 + 65536);

    prep_kernel<<<4096, 256, 0, stream>>>(X, Xb, ex, nullptr, 16384);
    prep_kernel<<<2048, 256, 0, stream>>>(Y, Yb, cw, W, 8192);
    init_out<<<64, 256, 0, stream>>>(out, b, 16384);
    rbf_gemm<<<256, 512, 0, stream>>>(Xb, Yb, ex, cw, out);
}